// Round 4
// baseline (238.003 us; speedup 1.0000x reference)
//
#include <hip/hip_runtime.h>
#include <hip/hip_bf16.h>
#include <stdint.h>

#define DEV __device__ __forceinline__

typedef short s4v __attribute__((ext_vector_type(4)));   // 4 bf16 (bit pattern)
typedef float f4v __attribute__((ext_vector_type(4)));

static constexpr int T = 4096;
static constexpr int BATCH = 4;
static constexpr int MD = 64;
static constexpr int H = 16;
static constexpr int PB = T * H;        // 65536 permuted elements per batch
static constexpr int NCHUNK = 4;        // 4096 / 1024 s-chunks

// ---------------- mfma 16x16x16 bf16 (D = A[16x16k] * B[16kx16] + C) -------
#if __has_builtin(__builtin_amdgcn_mfma_f32_16x16x16bf16_1k)
DEV f4v mfma16(s4v a, s4v b, f4v c) {
    return __builtin_amdgcn_mfma_f32_16x16x16bf16_1k(a, b, c, 0, 0, 0);
}
#elif __has_builtin(__builtin_amdgcn_mfma_f32_16x16x16_bf16)
typedef __bf16 bf4v __attribute__((ext_vector_type(4)));
DEV f4v mfma16(s4v a, s4v b, f4v c) {
    return __builtin_amdgcn_mfma_f32_16x16x16_bf16(__builtin_bit_cast(bf4v, a),
                                                   __builtin_bit_cast(bf4v, b), c, 0, 0, 0);
}
#else
DEV f4v mfma16(s4v a, s4v b, f4v c) {
    asm("v_mfma_f32_16x16x16_bf16 %0, %1, %2, %0" : "+v"(c) : "v"(a), "v"(b));
    return c;
}
#endif

DEV short f2bf(float x) {               // fp32 -> bf16 RNE
    uint32_t u = __builtin_bit_cast(uint32_t, x);
    u += 0x7fffu + ((u >> 16) & 1u);
    return (short)(u >> 16);
}

DEV float ex2(float x) {
#if __has_builtin(__builtin_amdgcn_exp2f)
    return __builtin_amdgcn_exp2f(x);
#else
    return exp2f(x);
#endif
}

// ---------------------------------------------------------------------------
// K1: QKV projection -> permuted bf16 layout. Q is pre-scaled by 0.25*log2(e).
// Also zeroes the per-(b,tb) completion counters (256 of them) every call.
// Q/K perm: elem(b,t,h) = b*PB + (t>>4)*256 + (h>>2)*64 + (t&15)*4 + (h&3)
// V   perm: elem(b,t,h) = b*PB + (t>>4)*256 + ((t&15)>>2)*64 + h*4 + (t&3)
// ---------------------------------------------------------------------------
__global__ __launch_bounds__(256) void k_proj(
    const float* __restrict__ idx,
    const float* __restrict__ Wk, const float* __restrict__ bk,
    const float* __restrict__ Wq, const float* __restrict__ bq,
    const float* __restrict__ Wv, const float* __restrict__ bv,
    short* __restrict__ qp, short* __restrict__ kp, short* __restrict__ vp,
    int* __restrict__ cnt)
{
    if (threadIdx.x == 0) cnt[blockIdx.x] = 0;   // 256 blocks -> 256 counters

    const int w = threadIdx.x >> 6, lane = threadIdx.x & 63;
    const int a = lane & 15, g = lane >> 4;
    const int tile = blockIdx.x * 4 + w;        // 0..1023
    const int b = tile >> 8;
    const int trow0 = (tile & 255) << 4;

    const float* rb = idx + (size_t)(b * T + trow0) * MD;

    s4v xf[4], wqf[4], wkf[4], wvf[4];
#pragma unroll
    for (int kc = 0; kc < 4; ++kc) {
        const int ko = kc * 16 + 4 * g;
        f4v x = *(const f4v*)(rb + a * MD + ko);     // idx[t0+a][ko..ko+3]
        f4v q = *(const f4v*)(Wq + a * MD + ko);     // Wq[a][ko..]
        f4v k = *(const f4v*)(Wk + a * MD + ko);
        f4v v = *(const f4v*)(Wv + a * MD + ko);
        xf[kc]  = s4v{f2bf(x.x), f2bf(x.y), f2bf(x.z), f2bf(x.w)};
        wqf[kc] = s4v{f2bf(q.x), f2bf(q.y), f2bf(q.z), f2bf(q.w)};
        wkf[kc] = s4v{f2bf(k.x), f2bf(k.y), f2bf(k.z), f2bf(k.w)};
        wvf[kc] = s4v{f2bf(v.x), f2bf(v.y), f2bf(v.z), f2bf(v.w)};
    }
    f4v aq = {0.f,0.f,0.f,0.f}, ak = {0.f,0.f,0.f,0.f}, av = {0.f,0.f,0.f,0.f};
#pragma unroll
    for (int kc = 0; kc < 4; ++kc) {
        aq = mfma16(wqf[kc], xf[kc], aq);   // D^T[h][t]: lane t=t0+a, h=4g+r
        ak = mfma16(wkf[kc], xf[kc], ak);
        av = mfma16(xf[kc], wvf[kc], av);   // D[t][h]: lane h=a, t=t0+4g+r
    }
    const int slot = b * PB + (tile & 255) * 256 + g * 64 + a * 4;
    f4v bqv = *(const f4v*)(bq + 4 * g);
    f4v bkv = *(const f4v*)(bk + 4 * g);
    const float bvs = bv[a];
    const float CS = 0.36067376022224085f;      // 0.25 * log2(e), folded into Q
    *(s4v*)(qp + slot) = s4v{f2bf((aq.x + bqv.x) * CS), f2bf((aq.y + bqv.y) * CS),
                             f2bf((aq.z + bqv.z) * CS), f2bf((aq.w + bqv.w) * CS)};
    *(s4v*)(kp + slot) = s4v{f2bf(ak.x + bkv.x), f2bf(ak.y + bkv.y),
                             f2bf(ak.z + bkv.z), f2bf(ak.w + bkv.w)};
    *(s4v*)(vp + slot) = s4v{f2bf(av.x + bvs), f2bf(av.y + bvs),
                             f2bf(av.z + bvs), f2bf(av.w + bvs)};
}

// ---------------------------------------------------------------------------
// K2: flash attention partials + fused combine/output projection.
// Attention core is byte-identical to round 3 (single LDS buffer, 2 barriers
// per sub, issue-early prefetch, unrolled 4-tile masked compute, f2bf pack).
// After writing chunk partials, the LAST block of each (b,tb) (via a
// device-scope atomic counter) sums the <=4 chunk partials in ascending-c
// order (bitwise identical to the old k_out) and applies the Wp projection.
// ---------------------------------------------------------------------------
__global__ __launch_bounds__(256) void k_attn(
    const short* __restrict__ qp, const short* __restrict__ kp,
    const short* __restrict__ vp,
    float* __restrict__ avU, float* __restrict__ lsum,
    int* __restrict__ cnt,
    const float* __restrict__ Wp, const float* __restrict__ bp,
    float* __restrict__ out)
{
    const int bx = blockIdx.x;
    const int c = bx & 3, tb = (bx >> 2) & 63, b = bx >> 8;
    const int tmax = tb * 64 + 63;
    const int s_lo = c << 10;
    if (s_lo > tmax) return;                 // whole block exits: no barriers yet
    const int s_hi = min(s_lo + 1024, tmax + 1);

    const int tid = threadIdx.x;
    const int w = tid >> 6, lane = tid & 63;
    const int a = lane & 15, g = lane >> 4;
    const int t0w = tb * 64 + w * 16;
    const int tq = t0w + a;              // this lane's query row

    __shared__ __align__(16) short lds[2048];   // [0:1024)=K, [1024:2048)=V
    __shared__ int isLast;

    const s4v Qf = *(const s4v*)(qp + b * PB + (t0w >> 4) * 256 + g * 64 + a * 4);

    // staging addresses: thread tt copies 16B; waves 0-1 stage K, 2-3 stage V
    const short* sbase = ((tid & 128) ? vp : kp) + b * PB + (tid & 127) * 8;
    const int ldso = ((tid & 128) ? 1024 : 0) + (tid & 127) * 8;

    f4v acc = {0.f, 0.f, 0.f, 0.f};
    float lp = 0.f;

    const int nsub = (s_hi - s_lo + 63) >> 6;
    // prologue: stage sub 0
    *(uint4*)&lds[ldso] = *(const uint4*)(sbase + s_lo * 16);
    __syncthreads();

    for (int sub = 0; sub < nsub; ++sub) {
        const int s0 = s_lo + (sub << 6);
        const bool do_stage = (sub + 1 < nsub);
        uint4 stg;
        if (do_stage)                                   // issue early
            stg = *(const uint4*)(sbase + (s0 + 64) * 16);

        if (s0 <= t0w + 15) {                           // wave-uniform
            s4v Kf[4], Vf[4];
#pragma unroll
            for (int ti = 0; ti < 4; ++ti) {
                Kf[ti] = *(const s4v*)&lds[ti * 256 + g * 64 + a * 4];
                Vf[ti] = *(const s4v*)&lds[1024 + ti * 256 + g * 64 + a * 4];
            }
#pragma unroll
            for (int ti = 0; ti < 4; ++ti) {
                f4v S = mfma16(Kf[ti], Qf, f4v{0.f,0.f,0.f,0.f});
                const int sb = s0 + ti * 16 + 4 * g;    // S[r]=(s=sb+r, q=tq)
                f4v p;
#pragma unroll
                for (int r = 0; r < 4; ++r) {
                    const float e = ex2(S[r]);
                    p[r] = (sb + r <= tq) ? e : 0.f;
                }
                lp += p.x + p.y + p.z + p.w;
                const s4v Pf = s4v{f2bf(p.x), f2bf(p.y), f2bf(p.z), f2bf(p.w)};
                acc = mfma16(Pf, Vf[ti], acc);   // acc[r] = avU(q=t0w+4g+r, h=a)
            }
        }
        __syncthreads();                                // all reads done
        if (do_stage)
            *(uint4*)&lds[ldso] = stg;                  // write late
        __syncthreads();                                // write visible
    }

    // ---- write this chunk's partials (guard never fires for valid blocks,
    //      kept for safety; no early return — barriers follow) ----
    if (s_lo <= t0w + 15) {
        float l2 = lp + __shfl_xor(lp, 16);  // row-sum over the 4 lane groups
        l2 += __shfl_xor(l2, 32);

        const int cb = c * 4 + b;
        float* ob = avU + ((size_t)cb * T + t0w) * 16;
#pragma unroll
        for (int r = 0; r < 4; ++r)
            ob[(4 * g + r) * 16 + a] = acc[r];
        if (lane < 16)
            lsum[cb * T + t0w + lane] = l2;
    }

    // ---- completion counting: last chunk block of (b,tb) combines ----
    __threadfence();                         // release partials (device scope)
    __syncthreads();
    const int nch = (tb >> 4) + 1;           // chunks feeding this (b,tb)
    if (tid == 0) {
        const int old = atomicAdd(&cnt[b * 64 + tb], 1);
        isLast = (old == nch - 1) ? 1 : 0;
    }
    __syncthreads();
    if (!isLast) return;
    __threadfence();                         // acquire all chunks' partials

    // ---- combine + output projection: 256 threads = 64 rows x 4 d-chunks --
    {
        const int i = tid & 63, dc = tid >> 6;
        const int t = tb * 64 + i;

        float av[16];
#pragma unroll
        for (int h = 0; h < 16; ++h) av[h] = 0.f;
        float l = 0.f;
        for (int cc = 0; cc < nch; ++cc) {
            const int cb2 = cc * 4 + b;
            const float* pa = avU + ((size_t)cb2 * T + t) * 16;
#pragma unroll
            for (int q4 = 0; q4 < 4; ++q4) {
                f4v x = *(const f4v*)(pa + q4 * 4);
                av[q4 * 4 + 0] += x.x; av[q4 * 4 + 1] += x.y;
                av[q4 * 4 + 2] += x.z; av[q4 * 4 + 3] += x.w;
            }
            l += lsum[cb2 * T + t];
        }
        const float inv = 1.f / l;

        float* orow = out + (size_t)(b * T + t) * 64 + dc * 16;
#pragma unroll
        for (int j4 = 0; j4 < 4; ++j4) {
            f4v o;
#pragma unroll
            for (int jj = 0; jj < 4; ++jj) {
                const int d = dc * 16 + j4 * 4 + jj;
                const float* wr = Wp + d * 16;
                float s = 0.f;
#pragma unroll
                for (int h = 0; h < 16; ++h) s += av[h] * wr[h];
                o[jj] = bp[d] + s * inv;
            }
            *(f4v*)(orow + j4 * 4) = o;
        }
    }
}

// ---------------------------------------------------------------------------
// ws layout: qp 512K | kp 512K | vp 512K | avU 4M | lsum 256K | cnt 1K
// ---------------------------------------------------------------------------
extern "C" void kernel_launch(void* const* d_in, const int* in_sizes, int n_in,
                              void* d_out, int out_size, void* d_ws, size_t ws_size,
                              hipStream_t stream) {
    const float* idx = (const float*)d_in[0];
    const float* Wk  = (const float*)d_in[1];
    const float* bk  = (const float*)d_in[2];
    const float* Wq  = (const float*)d_in[3];
    const float* bq  = (const float*)d_in[4];
    const float* Wv  = (const float*)d_in[5];
    const float* bv  = (const float*)d_in[6];
    const float* Wp  = (const float*)d_in[7];
    const float* bp  = (const float*)d_in[8];
    float* out = (float*)d_out;

    short* qp = (short*)d_ws;
    short* kp = qp + BATCH * PB;
    short* vp = kp + BATCH * PB;
    float* avU  = (float*)(vp + BATCH * PB);
    float* lsum = avU + (size_t)NCHUNK * BATCH * T * H;
    int*   cnt  = (int*)(lsum + (size_t)NCHUNK * BATCH * T);

    k_proj<<<256, 256, 0, stream>>>(idx, Wk, bk, Wq, bq, Wv, bv, qp, kp, vp, cnt);
    k_attn<<<1024, 256, 0, stream>>>(qp, kp, vp, avU, lsum, cnt, Wp, bp, out);
}

// Round 5
// 39.355 us; speedup vs baseline: 6.0476x; 6.0476x over previous
//
#include <hip/hip_runtime.h>
#include <hip/hip_bf16.h>
#include <stdint.h>

#define DEV __device__ __forceinline__

typedef short s4v __attribute__((ext_vector_type(4)));   // 4 bf16 (bit pattern)
typedef float f4v __attribute__((ext_vector_type(4)));

static constexpr int T = 4096;
static constexpr int BATCH = 4;
static constexpr int MD = 64;
static constexpr int H = 16;
static constexpr int PB = T * H;        // 65536 permuted elements per batch
static constexpr int NCHUNK = 4;        // 4096 / 1024 s-chunks

// ---------------- mfma 16x16x16 bf16 (D = A[16x16k] * B[16kx16] + C) -------
#if __has_builtin(__builtin_amdgcn_mfma_f32_16x16x16bf16_1k)
DEV f4v mfma16(s4v a, s4v b, f4v c) {
    return __builtin_amdgcn_mfma_f32_16x16x16bf16_1k(a, b, c, 0, 0, 0);
}
#elif __has_builtin(__builtin_amdgcn_mfma_f32_16x16x16_bf16)
typedef __bf16 bf4v __attribute__((ext_vector_type(4)));
DEV f4v mfma16(s4v a, s4v b, f4v c) {
    return __builtin_amdgcn_mfma_f32_16x16x16_bf16(__builtin_bit_cast(bf4v, a),
                                                   __builtin_bit_cast(bf4v, b), c, 0, 0, 0);
}
#else
DEV f4v mfma16(s4v a, s4v b, f4v c) {
    asm("v_mfma_f32_16x16x16_bf16 %0, %1, %2, %0" : "+v"(c) : "v"(a), "v"(b));
    return c;
}
#endif

DEV short f2bf(float x) {               // fp32 -> bf16 RNE
    uint32_t u = __builtin_bit_cast(uint32_t, x);
    u += 0x7fffu + ((u >> 16) & 1u);
    return (short)(u >> 16);
}

DEV float ex2(float x) {
#if __has_builtin(__builtin_amdgcn_exp2f)
    return __builtin_amdgcn_exp2f(x);
#else
    return exp2f(x);
#endif
}

// ---------------------------------------------------------------------------
// K1: QKV projection -> permuted bf16 layout. Q is pre-scaled by 0.25*log2(e)
// so the attention kernel applies exp2 directly to the MFMA output.
// Q/K perm: elem(b,t,h) = b*PB + (t>>4)*256 + (h>>2)*64 + (t&15)*4 + (h&3)
// V   perm: elem(b,t,h) = b*PB + (t>>4)*256 + ((t&15)>>2)*64 + h*4 + (t&3)
// ---------------------------------------------------------------------------
__global__ __launch_bounds__(256) void k_proj(
    const float* __restrict__ idx,
    const float* __restrict__ Wk, const float* __restrict__ bk,
    const float* __restrict__ Wq, const float* __restrict__ bq,
    const float* __restrict__ Wv, const float* __restrict__ bv,
    short* __restrict__ qp, short* __restrict__ kp, short* __restrict__ vp)
{
    const int w = threadIdx.x >> 6, lane = threadIdx.x & 63;
    const int a = lane & 15, g = lane >> 4;
    const int tile = blockIdx.x * 4 + w;        // 0..1023
    const int b = tile >> 8;
    const int trow0 = (tile & 255) << 4;

    const float* rb = idx + (size_t)(b * T + trow0) * MD;

    s4v xf[4], wqf[4], wkf[4], wvf[4];
#pragma unroll
    for (int kc = 0; kc < 4; ++kc) {
        const int ko = kc * 16 + 4 * g;
        f4v x = *(const f4v*)(rb + a * MD + ko);     // idx[t0+a][ko..ko+3]
        f4v q = *(const f4v*)(Wq + a * MD + ko);     // Wq[a][ko..]
        f4v k = *(const f4v*)(Wk + a * MD + ko);
        f4v v = *(const f4v*)(Wv + a * MD + ko);
        xf[kc]  = s4v{f2bf(x.x), f2bf(x.y), f2bf(x.z), f2bf(x.w)};
        wqf[kc] = s4v{f2bf(q.x), f2bf(q.y), f2bf(q.z), f2bf(q.w)};
        wkf[kc] = s4v{f2bf(k.x), f2bf(k.y), f2bf(k.z), f2bf(k.w)};
        wvf[kc] = s4v{f2bf(v.x), f2bf(v.y), f2bf(v.z), f2bf(v.w)};
    }
    f4v aq = {0.f,0.f,0.f,0.f}, ak = {0.f,0.f,0.f,0.f}, av = {0.f,0.f,0.f,0.f};
#pragma unroll
    for (int kc = 0; kc < 4; ++kc) {
        aq = mfma16(wqf[kc], xf[kc], aq);   // D^T[h][t]: lane t=t0+a, h=4g+r
        ak = mfma16(wkf[kc], xf[kc], ak);
        av = mfma16(xf[kc], wvf[kc], av);   // D[t][h]: lane h=a, t=t0+4g+r
    }
    const int slot = b * PB + (tile & 255) * 256 + g * 64 + a * 4;
    f4v bqv = *(const f4v*)(bq + 4 * g);
    f4v bkv = *(const f4v*)(bk + 4 * g);
    const float bvs = bv[a];
    const float CS = 0.36067376022224085f;      // 0.25 * log2(e), folded into Q
    *(s4v*)(qp + slot) = s4v{f2bf((aq.x + bqv.x) * CS), f2bf((aq.y + bqv.y) * CS),
                             f2bf((aq.z + bqv.z) * CS), f2bf((aq.w + bqv.w) * CS)};
    *(s4v*)(kp + slot) = s4v{f2bf(ak.x + bkv.x), f2bf(ak.y + bkv.y),
                             f2bf(ak.z + bkv.z), f2bf(ak.w + bkv.w)};
    *(s4v*)(vp + slot) = s4v{f2bf(av.x + bvs), f2bf(av.y + bvs),
                             f2bf(av.z + bvs), f2bf(av.w + bvs)};
}

// ---------------------------------------------------------------------------
// K2: flash attention partials — PER-WAVE INDEPENDENT (round 5).
// No LDS, no barriers, no fences. Each wave = one (b, q-tile, chunk) task,
// reading K/V fragments straight from L2 (coalesced 512B bursts via the
// permuted layout), 4-tile unrolled groups for load/compute overlap.
// Overshoot tiles within a group are masked via slim (reads stay in-bounds:
// tile index <= st0+63 <= 255 always). Accumulation order identical to
// round 3 -> bitwise-identical avU/lsum.
// ---------------------------------------------------------------------------
__global__ __launch_bounds__(256) void k_attn(
    const short* __restrict__ qp, const short* __restrict__ kp,
    const short* __restrict__ vp,
    float* __restrict__ avU, float* __restrict__ lsum)
{
    const int bx = blockIdx.x;
    const int c = bx & 3, tb = (bx >> 2) & 63, b = bx >> 8;
    const int s_lo = c << 10;
    if (s_lo > tb * 64 + 63) return;             // block-level cull

    const int w = threadIdx.x >> 6, lane = threadIdx.x & 63;
    const int a = lane & 15, g = lane >> 4;
    const int qt = tb * 4 + w;                   // this wave's q-tile (16 rows)
    const int t0w = qt * 16;
    const int tq = t0w + a;                      // this lane's query row
    if (s_lo > t0w + 15) return;                 // wave-level cull (no barriers)

    const s4v Qf = *(const s4v*)(qp + b * PB + qt * 256 + g * 64 + a * 4);

    const int st0 = s_lo >> 4;                           // first s-tile
    const int lastS = min(t0w + 15, s_lo + 1023);        // last s-row needed
    const int nst = (lastS >> 4) - st0 + 1;              // 1..64 tiles
    const int slim = min(tq, s_lo + 1023);               // per-lane mask bound

    const short* kb = kp + b * PB + st0 * 256 + g * 64 + a * 4;
    const short* vb = vp + b * PB + st0 * 256 + g * 64 + a * 4;

    f4v acc = {0.f, 0.f, 0.f, 0.f};
    float lp = 0.f;

    const int nit = (nst + 3) >> 2;              // 4-tile groups
    for (int it = 0; it < nit; ++it) {
        const int tbase = it * 4;
        s4v Kf[4], Vf[4];
#pragma unroll
        for (int u = 0; u < 4; ++u) {
            Kf[u] = *(const s4v*)(kb + (tbase + u) * 256);
            Vf[u] = *(const s4v*)(vb + (tbase + u) * 256);
        }
#pragma unroll
        for (int u = 0; u < 4; ++u) {
            f4v S = mfma16(Kf[u], Qf, f4v{0.f,0.f,0.f,0.f});
            const int sb = s_lo + (tbase + u) * 16 + 4 * g;  // S[r]=(s=sb+r,q=tq)
            f4v p;
#pragma unroll
            for (int r = 0; r < 4; ++r) {
                const float e = ex2(S[r]);
                p[r] = (sb + r <= slim) ? e : 0.f;
            }
            lp += p.x + p.y + p.z + p.w;
            const s4v Pf = s4v{f2bf(p.x), f2bf(p.y), f2bf(p.z), f2bf(p.w)};
            acc = mfma16(Pf, Vf[u], acc);        // acc[r]=avU(q=t0w+4g+r, h=a)
        }
    }

    lp += __shfl_xor(lp, 16);        // row-sum over the 4 lane groups
    lp += __shfl_xor(lp, 32);

    const int cb = c * 4 + b;
    float* ob = avU + ((size_t)cb * T + t0w) * 16;
#pragma unroll
    for (int r = 0; r < 4; ++r)
        ob[(4 * g + r) * 16 + a] = acc[r];
    if (lane < 16)
        lsum[cb * T + t0w + lane] = lp;
}

// ---------------------------------------------------------------------------
// K3: combine chunk partials, normalize, fused output projection (+bp).
// 65536 threads: row = gid & 16383 (coalesced), d-chunk of 16 = gid >> 14.
// ---------------------------------------------------------------------------
__global__ __launch_bounds__(256) void k_out(
    const float* __restrict__ avU, const float* __restrict__ lsum,
    const float* __restrict__ Wp, const float* __restrict__ bp,
    float* __restrict__ out)
{
    const int gid = blockIdx.x * 256 + threadIdx.x;
    const int row = gid & 16383;
    const int dc = gid >> 14;
    const int b = row >> 12, t = row & 4095;
    const int nch = (t >> 10) + 1;

    float av[16];
#pragma unroll
    for (int h = 0; h < 16; ++h) av[h] = 0.f;
    float l = 0.f;
    for (int c = 0; c < nch; ++c) {
        const int cb = c * 4 + b;
        const float* pa = avU + ((size_t)cb * T + t) * 16;
#pragma unroll
        for (int q4 = 0; q4 < 4; ++q4) {
            f4v x = *(const f4v*)(pa + q4 * 4);
            av[q4 * 4 + 0] += x.x; av[q4 * 4 + 1] += x.y;
            av[q4 * 4 + 2] += x.z; av[q4 * 4 + 3] += x.w;
        }
        l += lsum[cb * T + t];
    }
    const float inv = 1.f / l;

    float* orow = out + (size_t)row * 64 + dc * 16;
#pragma unroll
    for (int j4 = 0; j4 < 4; ++j4) {
        f4v o;
#pragma unroll
        for (int jj = 0; jj < 4; ++jj) {
            const int d = dc * 16 + j4 * 4 + jj;
            const float* wr = Wp + d * 16;
            float s = 0.f;
#pragma unroll
            for (int h = 0; h < 16; ++h) s += av[h] * wr[h];
            o[jj] = bp[d] + s * inv;
        }
        *(f4v*)(orow + j4 * 4) = o;
    }
}

// ---------------------------------------------------------------------------
// ws layout (bytes): qp 512K | kp 512K | vp 512K | avU 4M | lsum 256K  (~5.75MB)
// ---------------------------------------------------------------------------
extern "C" void kernel_launch(void* const* d_in, const int* in_sizes, int n_in,
                              void* d_out, int out_size, void* d_ws, size_t ws_size,
                              hipStream_t stream) {
    const float* idx = (const float*)d_in[0];
    const float* Wk  = (const float*)d_in[1];
    const float* bk  = (const float*)d_in[2];
    const float* Wq  = (const float*)d_in[3];
    const float* bq  = (const float*)d_in[4];
    const float* Wv  = (const float*)d_in[5];
    const float* bv  = (const float*)d_in[6];
    const float* Wp  = (const float*)d_in[7];
    const float* bp  = (const float*)d_in[8];
    float* out = (float*)d_out;

    short* qp = (short*)d_ws;
    short* kp = qp + BATCH * PB;
    short* vp = kp + BATCH * PB;
    float* avU  = (float*)(vp + BATCH * PB);
    float* lsum = avU + (size_t)NCHUNK * BATCH * T * H;

    k_proj<<<256, 256, 0, stream>>>(idx, Wk, bk, Wq, bq, Wv, bv, qp, kp, vp);
    k_attn<<<1024, 256, 0, stream>>>(qp, kp, vp, avU, lsum);
    k_out<<<256, 256, 0, stream>>>(avU, lsum, Wp, bp, out);
}

// Round 6
// 31.373 us; speedup vs baseline: 7.5863x; 1.2544x over previous
//
#include <hip/hip_runtime.h>
#include <hip/hip_bf16.h>
#include <stdint.h>

#define DEV __device__ __forceinline__

typedef short s4v __attribute__((ext_vector_type(4)));   // 4 bf16 (bit pattern)
typedef float f4v __attribute__((ext_vector_type(4)));

static constexpr int T = 4096;
static constexpr int BATCH = 4;
static constexpr int MD = 64;
static constexpr int H = 16;
static constexpr int PB = T * H;        // 65536 permuted elements per batch

// ---------------- mfma 16x16x16 bf16 (D = A[16x16k] * B[16kx16] + C) -------
#if __has_builtin(__builtin_amdgcn_mfma_f32_16x16x16bf16_1k)
DEV f4v mfma16(s4v a, s4v b, f4v c) {
    return __builtin_amdgcn_mfma_f32_16x16x16bf16_1k(a, b, c, 0, 0, 0);
}
#elif __has_builtin(__builtin_amdgcn_mfma_f32_16x16x16_bf16)
typedef __bf16 bf4v __attribute__((ext_vector_type(4)));
DEV f4v mfma16(s4v a, s4v b, f4v c) {
    return __builtin_amdgcn_mfma_f32_16x16x16_bf16(__builtin_bit_cast(bf4v, a),
                                                   __builtin_bit_cast(bf4v, b), c, 0, 0, 0);
}
#else
DEV f4v mfma16(s4v a, s4v b, f4v c) {
    asm("v_mfma_f32_16x16x16_bf16 %0, %1, %2, %0" : "+v"(c) : "v"(a), "v"(b));
    return c;
}
#endif

DEV short f2bf(float x) {               // fp32 -> bf16 RNE
    uint32_t u = __builtin_bit_cast(uint32_t, x);
    u += 0x7fffu + ((u >> 16) & 1u);
    return (short)(u >> 16);
}

DEV float ex2(float x) {
#if __has_builtin(__builtin_amdgcn_exp2f)
    return __builtin_amdgcn_exp2f(x);
#else
    return exp2f(x);
#endif
}

// ---------------------------------------------------------------------------
// K1: QKV projection -> permuted bf16 layout. Q is pre-scaled by 0.25*log2(e)
// so the attention kernel applies exp2 directly to the MFMA output.
// Q/K perm: elem(b,t,h) = b*PB + (t>>4)*256 + (h>>2)*64 + (t&15)*4 + (h&3)
// V   perm: elem(b,t,h) = b*PB + (t>>4)*256 + ((t&15)>>2)*64 + h*4 + (t&3)
// ---------------------------------------------------------------------------
__global__ __launch_bounds__(256) void k_proj(
    const float* __restrict__ idx,
    const float* __restrict__ Wk, const float* __restrict__ bk,
    const float* __restrict__ Wq, const float* __restrict__ bq,
    const float* __restrict__ Wv, const float* __restrict__ bv,
    short* __restrict__ qp, short* __restrict__ kp, short* __restrict__ vp)
{
    const int w = threadIdx.x >> 6, lane = threadIdx.x & 63;
    const int a = lane & 15, g = lane >> 4;
    const int tile = blockIdx.x * 4 + w;        // 0..1023
    const int b = tile >> 8;
    const int trow0 = (tile & 255) << 4;

    const float* rb = idx + (size_t)(b * T + trow0) * MD;

    s4v xf[4], wqf[4], wkf[4], wvf[4];
#pragma unroll
    for (int kc = 0; kc < 4; ++kc) {
        const int ko = kc * 16 + 4 * g;
        f4v x = *(const f4v*)(rb + a * MD + ko);     // idx[t0+a][ko..ko+3]
        f4v q = *(const f4v*)(Wq + a * MD + ko);     // Wq[a][ko..]
        f4v k = *(const f4v*)(Wk + a * MD + ko);
        f4v v = *(const f4v*)(Wv + a * MD + ko);
        xf[kc]  = s4v{f2bf(x.x), f2bf(x.y), f2bf(x.z), f2bf(x.w)};
        wqf[kc] = s4v{f2bf(q.x), f2bf(q.y), f2bf(q.z), f2bf(q.w)};
        wkf[kc] = s4v{f2bf(k.x), f2bf(k.y), f2bf(k.z), f2bf(k.w)};
        wvf[kc] = s4v{f2bf(v.x), f2bf(v.y), f2bf(v.z), f2bf(v.w)};
    }
    f4v aq = {0.f,0.f,0.f,0.f}, ak = {0.f,0.f,0.f,0.f}, av = {0.f,0.f,0.f,0.f};
#pragma unroll
    for (int kc = 0; kc < 4; ++kc) {
        aq = mfma16(wqf[kc], xf[kc], aq);   // D^T[h][t]: lane t=t0+a, h=4g+r
        ak = mfma16(wkf[kc], xf[kc], ak);
        av = mfma16(xf[kc], wvf[kc], av);   // D[t][h]: lane h=a, t=t0+4g+r
    }
    const int slot = b * PB + (tile & 255) * 256 + g * 64 + a * 4;
    f4v bqv = *(const f4v*)(bq + 4 * g);
    f4v bkv = *(const f4v*)(bk + 4 * g);
    const float bvs = bv[a];
    const float CS = 0.36067376022224085f;      // 0.25 * log2(e), folded into Q
    *(s4v*)(qp + slot) = s4v{f2bf((aq.x + bqv.x) * CS), f2bf((aq.y + bqv.y) * CS),
                             f2bf((aq.z + bqv.z) * CS), f2bf((aq.w + bqv.w) * CS)};
    *(s4v*)(kp + slot) = s4v{f2bf(ak.x + bkv.x), f2bf(ak.y + bkv.y),
                             f2bf(ak.z + bkv.z), f2bf(ak.w + bkv.w)};
    *(s4v*)(vp + slot) = s4v{f2bf(av.x + bvs), f2bf(av.y + bvs),
                             f2bf(av.z + bvs), f2bf(av.w + bvs)};
}

// ---- attention over s-tiles [lo, hi) for one Q fragment, accumulating ----
DEV void proc_range(int lo, int hi, s4v Qf, int tq, int g,
                    const short* __restrict__ kb, const short* __restrict__ vb,
                    f4v& acc, float& lp)
{
    int st = lo;
    for (; st + 4 <= hi; st += 4) {          // 4-tile groups: 8 loads in flight
        s4v Kf[4], Vf[4];
#pragma unroll
        for (int u = 0; u < 4; ++u) {
            Kf[u] = *(const s4v*)(kb + (st + u) * 256);
            Vf[u] = *(const s4v*)(vb + (st + u) * 256);
        }
#pragma unroll
        for (int u = 0; u < 4; ++u) {
            f4v S = mfma16(Kf[u], Qf, f4v{0.f,0.f,0.f,0.f});
            const int sb = (st + u) * 16 + 4 * g;     // S[r] = (s=sb+r, q=tq)
            f4v p;
#pragma unroll
            for (int r = 0; r < 4; ++r) {
                const float e = ex2(S[r]);
                p[r] = (sb + r <= tq) ? e : 0.f;
            }
            lp += p.x + p.y + p.z + p.w;
            const s4v Pf = s4v{f2bf(p.x), f2bf(p.y), f2bf(p.z), f2bf(p.w)};
            acc = mfma16(Pf, Vf[u], acc);
        }
    }
    for (; st < hi; ++st) {                  // tail (0..3 tiles)
        s4v Kf = *(const s4v*)(kb + st * 256);
        s4v Vf = *(const s4v*)(vb + st * 256);
        f4v S = mfma16(Kf, Qf, f4v{0.f,0.f,0.f,0.f});
        const int sb = st * 16 + 4 * g;
        f4v p;
#pragma unroll
        for (int r = 0; r < 4; ++r) {
            const float e = ex2(S[r]);
            p[r] = (sb + r <= tq) ? e : 0.f;
        }
        lp += p.x + p.y + p.z + p.w;
        const s4v Pf = s4v{f2bf(p.x), f2bf(p.y), f2bf(p.z), f2bf(p.w)};
        acc = mfma16(Pf, Vf, acc);
    }
}

// ---------------------------------------------------------------------------
// K2 (fused): attention + block-local combine + output projection.
// Grid 512 = (b:4) x (pair j:128). Block owns q-tiles {j, 255-j}: causal
// s-tile counts (j+1) + (256-j) = 257 = constant -> perfect load balance.
// The 4 waves split the concatenated tile list [A(0..j) ++ B(0..255-j)]
// into 65/65/65/62 slices; partials (acc, lsum) combined via LDS with one
// __syncthreads (block-local -> no device fence, no atomics).
// ---------------------------------------------------------------------------
__global__ __launch_bounds__(256) void k_fused(
    const short* __restrict__ qp, const short* __restrict__ kp,
    const short* __restrict__ vp,
    const float* __restrict__ Wp, const float* __restrict__ bp,
    float* __restrict__ out)
{
    const int bx = blockIdx.x;
    const int b = bx >> 7, j = bx & 127;
    const int tid = threadIdx.x;
    const int w = tid >> 6, lane = tid & 63;
    const int a = lane & 15, g = lane >> 4;

    const int qtA = j, qtB = 255 - j;
    const int ntA = j + 1;               // A s-tiles: [0, ntA)
    const int ntot = 257;                // ntA + (256 - j)

    const short* qb = qp + b * PB;
    const short* kb = kp + b * PB + g * 64 + a * 4;
    const short* vb = vp + b * PB + g * 64 + a * 4;

    const s4v QfA = *(const s4v*)(qb + qtA * 256 + g * 64 + a * 4);
    const s4v QfB = *(const s4v*)(qb + qtB * 256 + g * 64 + a * 4);
    const int tqA = qtA * 16 + a, tqB = qtB * 16 + a;

    // this wave's slice of the virtual tile list
    const int vLo = min(w * 65, ntot);
    const int vHi = min(vLo + 65, ntot);

    f4v accA = {0.f,0.f,0.f,0.f}, accB = {0.f,0.f,0.f,0.f};
    float lpA = 0.f, lpB = 0.f;

    // A part: virtual [vLo, min(vHi,ntA)) -> st same range
    proc_range(vLo, min(vHi, ntA), QfA, tqA, g, kb, vb, accA, lpA);
    // B part: virtual [max(vLo,ntA), vHi) -> st = vt - ntA
    proc_range(max(vLo - ntA, 0), vHi - ntA, QfB, tqB, g, kb, vb, accB, lpB);

    __shared__ float pacc[8 * 64 * 4];   // [(w*2+X)*64 + lane][r]
    __shared__ float plp[8 * 16];        // [(w*2+X)*16 + row]

    *(f4v*)&pacc[((w * 2 + 0) * 64 + lane) * 4] = accA;
    *(f4v*)&pacc[((w * 2 + 1) * 64 + lane) * 4] = accB;

    float lA = lpA + __shfl_xor(lpA, 16); lA += __shfl_xor(lA, 32);
    float lB = lpB + __shfl_xor(lpB, 16); lB += __shfl_xor(lB, 32);
    if (lane < 16) {
        plp[(w * 2 + 0) * 16 + lane] = lA;
        plp[(w * 2 + 1) * 16 + lane] = lB;
    }
    __syncthreads();

    // combine + normalize + output projection: 128 tasks = (X:2, row:16, dc:4)
    if (tid < 128) {
        const int X = tid >> 6, i = (tid >> 2) & 15, dc = tid & 3;
        float av[16];
#pragma unroll
        for (int h = 0; h < 16; ++h) av[h] = 0.f;
        float l = 0.f;
#pragma unroll
        for (int ww = 0; ww < 4; ++ww) {     // fixed wave order: deterministic
            const int base = ((ww * 2 + X) * 64 + (i >> 2) * 16) * 4 + (i & 3);
#pragma unroll
            for (int h = 0; h < 16; ++h) av[h] += pacc[base + h * 4];
            l += plp[(ww * 2 + X) * 16 + i];
        }
        const float inv = 1.f / l;
        const int qt = X ? qtB : qtA;

        float* orow = out + ((size_t)(b * T) + qt * 16 + i) * 64 + dc * 16;
#pragma unroll
        for (int j4 = 0; j4 < 4; ++j4) {
            f4v o;
#pragma unroll
            for (int jj = 0; jj < 4; ++jj) {
                const int d = dc * 16 + j4 * 4 + jj;
                const float* wr = Wp + d * 16;
                float s = 0.f;
#pragma unroll
                for (int h = 0; h < 16; ++h) s += av[h] * wr[h];
                o[jj] = bp[d] + s * inv;
            }
            *(f4v*)(orow + j4 * 4) = o;
        }
    }
}

// ---------------------------------------------------------------------------
// ws layout (bytes): qp 512K | kp 512K | vp 512K   (1.5 MB)
// ---------------------------------------------------------------------------
extern "C" void kernel_launch(void* const* d_in, const int* in_sizes, int n_in,
                              void* d_out, int out_size, void* d_ws, size_t ws_size,
                              hipStream_t stream) {
    const float* idx = (const float*)d_in[0];
    const float* Wk  = (const float*)d_in[1];
    const float* bk  = (const float*)d_in[2];
    const float* Wq  = (const float*)d_in[3];
    const float* bq  = (const float*)d_in[4];
    const float* Wv  = (const float*)d_in[5];
    const float* bv  = (const float*)d_in[6];
    const float* Wp  = (const float*)d_in[7];
    const float* bp  = (const float*)d_in[8];
    float* out = (float*)d_out;

    short* qp = (short*)d_ws;
    short* kp = qp + BATCH * PB;
    short* vp = kp + BATCH * PB;

    k_proj<<<256, 256, 0, stream>>>(idx, Wk, bk, Wq, bq, Wv, bv, qp, kp, vp);
    k_fused<<<512, 256, 0, stream>>>(qp, kp, vp, Wp, bp, out);
}

// Round 8
// 31.119 us; speedup vs baseline: 7.6481x; 1.0081x over previous
//
#include <hip/hip_runtime.h>
#include <hip/hip_bf16.h>
#include <stdint.h>

#define DEV __device__ __forceinline__

typedef short s4v __attribute__((ext_vector_type(4)));   // 4 bf16 (bit pattern)
typedef float f4v __attribute__((ext_vector_type(4)));

static constexpr int T = 4096;
static constexpr int BATCH = 4;
static constexpr int MD = 64;
static constexpr int H = 16;
static constexpr int PB = T * H;        // 65536 permuted elements per batch

// ---------------- mfma 16x16x16 bf16 (D = A[16x16k] * B[16kx16] + C) -------
#if __has_builtin(__builtin_amdgcn_mfma_f32_16x16x16bf16_1k)
DEV f4v mfma16(s4v a, s4v b, f4v c) {
    return __builtin_amdgcn_mfma_f32_16x16x16bf16_1k(a, b, c, 0, 0, 0);
}
#elif __has_builtin(__builtin_amdgcn_mfma_f32_16x16x16_bf16)
typedef __bf16 bf4v __attribute__((ext_vector_type(4)));
DEV f4v mfma16(s4v a, s4v b, f4v c) {
    return __builtin_amdgcn_mfma_f32_16x16x16_bf16(__builtin_bit_cast(bf4v, a),
                                                   __builtin_bit_cast(bf4v, b), c, 0, 0, 0);
}
#else
DEV f4v mfma16(s4v a, s4v b, f4v c) {
    asm("v_mfma_f32_16x16x16_bf16 %0, %1, %2, %0" : "+v"(c) : "v"(a), "v"(b));
    return c;
}
#endif

DEV short f2bf(float x) {               // fp32 -> bf16 RNE (proven)
    uint32_t u = __builtin_bit_cast(uint32_t, x);
    u += 0x7fffu + ((u >> 16) & 1u);
    return (short)(u >> 16);
}

DEV s4v pack4(f4v p) {                  // 4x f2bf — the only proven pack
    return s4v{f2bf(p.x), f2bf(p.y), f2bf(p.z), f2bf(p.w)};
}

DEV float ex2(float x) {
#if __has_builtin(__builtin_amdgcn_exp2f)
    return __builtin_amdgcn_exp2f(x);
#else
    return exp2f(x);
#endif
}

// ---------------------------------------------------------------------------
// K1: QKV projection -> permuted bf16 layout. Q is pre-scaled by 0.25*log2(e)
// so the attention kernel applies exp2 directly to the MFMA output.
// (f2bf packing everywhere — v_cvt_pk_bf16_f32 produced NaNs in round 7.)
// Q/K perm: elem(b,t,h) = b*PB + (t>>4)*256 + (h>>2)*64 + (t&15)*4 + (h&3)
// V   perm: elem(b,t,h) = b*PB + (t>>4)*256 + ((t&15)>>2)*64 + h*4 + (t&3)
// ---------------------------------------------------------------------------
__global__ __launch_bounds__(256) void k_proj(
    const float* __restrict__ idx,
    const float* __restrict__ Wk, const float* __restrict__ bk,
    const float* __restrict__ Wq, const float* __restrict__ bq,
    const float* __restrict__ Wv, const float* __restrict__ bv,
    short* __restrict__ qp, short* __restrict__ kp, short* __restrict__ vp)
{
    const int w = threadIdx.x >> 6, lane = threadIdx.x & 63;
    const int a = lane & 15, g = lane >> 4;
    const int tile = blockIdx.x * 4 + w;        // 0..1023
    const int b = tile >> 8;
    const int trow0 = (tile & 255) << 4;

    const float* rb = idx + (size_t)(b * T + trow0) * MD;

    s4v xf[4], wqf[4], wkf[4], wvf[4];
#pragma unroll
    for (int kc = 0; kc < 4; ++kc) {
        const int ko = kc * 16 + 4 * g;
        f4v x = *(const f4v*)(rb + a * MD + ko);     // idx[t0+a][ko..ko+3]
        f4v q = *(const f4v*)(Wq + a * MD + ko);     // Wq[a][ko..]
        f4v k = *(const f4v*)(Wk + a * MD + ko);
        f4v v = *(const f4v*)(Wv + a * MD + ko);
        xf[kc]  = pack4(x);
        wqf[kc] = pack4(q);
        wkf[kc] = pack4(k);
        wvf[kc] = pack4(v);
    }
    f4v aq = {0.f,0.f,0.f,0.f}, ak = {0.f,0.f,0.f,0.f}, av = {0.f,0.f,0.f,0.f};
#pragma unroll
    for (int kc = 0; kc < 4; ++kc) {
        aq = mfma16(wqf[kc], xf[kc], aq);   // D^T[h][t]: lane t=t0+a, h=4g+r
        ak = mfma16(wkf[kc], xf[kc], ak);
        av = mfma16(xf[kc], wvf[kc], av);   // D[t][h]: lane h=a, t=t0+4g+r
    }
    const int slot = b * PB + (tile & 255) * 256 + g * 64 + a * 4;
    f4v bqv = *(const f4v*)(bq + 4 * g);
    f4v bkv = *(const f4v*)(bk + 4 * g);
    const float bvs = bv[a];
    const float CS = 0.36067376022224085f;      // 0.25 * log2(e), folded into Q
    f4v qv = {(aq.x + bqv.x) * CS, (aq.y + bqv.y) * CS,
              (aq.z + bqv.z) * CS, (aq.w + bqv.w) * CS};
    f4v kv = {ak.x + bkv.x, ak.y + bkv.y, ak.z + bkv.z, ak.w + bkv.w};
    f4v vv = {av.x + bvs, av.y + bvs, av.z + bvs, av.w + bvs};
    *(s4v*)(qp + slot) = pack4(qv);
    *(s4v*)(kp + slot) = pack4(kv);
    *(s4v*)(vp + slot) = pack4(vv);
}

// ---------------------------------------------------------------------------
// Attention over s-tiles [lo, hi) for one Q fragment.
// 8-tile groups, ping-pong prefetch (16 loads in flight under compute).
// Only the LAST group runs the guarded+causal-masked path; its loads are
// index-clamped to hi-1 (valid, finite memory) and padded tiles contribute
// exactly 0 (guard st+u < hi).
// ---------------------------------------------------------------------------
DEV void proc_range(int lo, int hi, s4v Qf, int tq, int g,
                    const short* __restrict__ kb, const short* __restrict__ vb,
                    f4v& acc, float& lp)
{
    if (lo >= hi) return;
    const int ng = (hi - lo + 7) >> 3;
    s4v KA[8], VA[8], KB[8], VB[8];

    auto LOADG = [&](s4v* K, s4v* V, int gi) {
        const int st = lo + gi * 8;
#pragma unroll
        for (int u = 0; u < 8; ++u) {
            const int idx = min(st + u, hi - 1);      // clamp tail padding
            K[u] = *(const s4v*)(kb + idx * 256);
            V[u] = *(const s4v*)(vb + idx * 256);
        }
    };
    auto COMPG = [&](const s4v* K, const s4v* V, int gi) {
        const int st = lo + gi * 8;
        if (gi == ng - 1) {                 // tail group: guarded + masked
#pragma unroll
            for (int u = 0; u < 8; ++u) {
                if (st + u < hi) {
                    f4v S = mfma16(K[u], Qf, f4v{0.f,0.f,0.f,0.f});
                    const int sb = (st + u) * 16 + 4 * g;
                    f4v p;
#pragma unroll
                    for (int r = 0; r < 4; ++r) {
                        const float e = ex2(S[r]);
                        p[r] = (sb + r <= tq) ? e : 0.f;
                    }
                    lp += p.x + p.y + p.z + p.w;
                    acc = mfma16(pack4(p), V[u], acc);
                }
            }
        } else {                            // full group: mask-free fast path
#pragma unroll
            for (int u = 0; u < 8; ++u) {
                f4v S = mfma16(K[u], Qf, f4v{0.f,0.f,0.f,0.f});
                f4v p;
#pragma unroll
                for (int r = 0; r < 4; ++r) p[r] = ex2(S[r]);
                lp += p.x + p.y + p.z + p.w;
                acc = mfma16(pack4(p), V[u], acc);
            }
        }
    };

    int it = 0;
    LOADG(KA, VA, 0);
    for (; it + 2 <= ng; it += 2) {
        LOADG(KB, VB, it + 1);
        COMPG(KA, VA, it);
        if (it + 2 < ng) LOADG(KA, VA, it + 2);
        COMPG(KB, VB, it + 1);
    }
    if (it < ng) COMPG(KA, VA, it);
}

// ---------------------------------------------------------------------------
// K2 (fused): attention + block-local combine + output projection.
// Grid 512 = (b:4) x (pair j:128). Block owns q-tiles {j, 255-j}: causal
// s-tile counts (j+1) + (256-j) = 257 = constant -> perfect load balance.
// The 4 waves split the concatenated tile list [A(0..j) ++ B(0..255-j)]
// into 65/65/65/62 slices; partials combined via LDS with one __syncthreads.
// ---------------------------------------------------------------------------
__global__ __launch_bounds__(256) void k_fused(
    const short* __restrict__ qp, const short* __restrict__ kp,
    const short* __restrict__ vp,
    const float* __restrict__ Wp, const float* __restrict__ bp,
    float* __restrict__ out)
{
    const int bx = blockIdx.x;
    const int b = bx >> 7, j = bx & 127;
    const int tid = threadIdx.x;
    const int w = tid >> 6, lane = tid & 63;
    const int a = lane & 15, g = lane >> 4;

    const int qtA = j, qtB = 255 - j;
    const int ntA = j + 1;               // A s-tiles: [0, ntA)
    const int ntot = 257;                // ntA + (256 - j)

    const short* qb = qp + b * PB;
    const short* kb = kp + b * PB + g * 64 + a * 4;
    const short* vb = vp + b * PB + g * 64 + a * 4;

    const s4v QfA = *(const s4v*)(qb + qtA * 256 + g * 64 + a * 4);
    const s4v QfB = *(const s4v*)(qb + qtB * 256 + g * 64 + a * 4);
    const int tqA = qtA * 16 + a, tqB = qtB * 16 + a;

    // this wave's slice of the virtual tile list
    const int vLo = min(w * 65, ntot);
    const int vHi = min(vLo + 65, ntot);

    f4v accA = {0.f,0.f,0.f,0.f}, accB = {0.f,0.f,0.f,0.f};
    float lpA = 0.f, lpB = 0.f;

    // A part: virtual [vLo, min(vHi,ntA)) -> st same range
    proc_range(vLo, min(vHi, ntA), QfA, tqA, g, kb, vb, accA, lpA);
    // B part: virtual [max(vLo,ntA), vHi) -> st = vt - ntA
    proc_range(max(vLo - ntA, 0), vHi - ntA, QfB, tqB, g, kb, vb, accB, lpB);

    __shared__ float pacc[8 * 64 * 4];   // [(w*2+X)*64 + lane][r]
    __shared__ float plp[8 * 16];        // [(w*2+X)*16 + row]

    *(f4v*)&pacc[((w * 2 + 0) * 64 + lane) * 4] = accA;
    *(f4v*)&pacc[((w * 2 + 1) * 64 + lane) * 4] = accB;

    float lA = lpA + __shfl_xor(lpA, 16); lA += __shfl_xor(lA, 32);
    float lB = lpB + __shfl_xor(lpB, 16); lB += __shfl_xor(lB, 32);
    if (lane < 16) {
        plp[(w * 2 + 0) * 16 + lane] = lA;
        plp[(w * 2 + 1) * 16 + lane] = lB;
    }
    __syncthreads();

    // combine + normalize + output projection: 128 tasks = (X:2, row:16, dc:4)
    if (tid < 128) {
        const int X = tid >> 6, i = (tid >> 2) & 15, dc = tid & 3;
        float av[16];
#pragma unroll
        for (int h = 0; h < 16; ++h) av[h] = 0.f;
        float l = 0.f;
#pragma unroll
        for (int ww = 0; ww < 4; ++ww) {     // fixed wave order: deterministic
            const int base = ((ww * 2 + X) * 64 + (i >> 2) * 16) * 4 + (i & 3);
#pragma unroll
            for (int h = 0; h < 16; ++h) av[h] += pacc[base + h * 4];
            l += plp[(ww * 2 + X) * 16 + i];
        }
        const float inv = 1.f / l;
        const int qt = X ? qtB : qtA;

        float* orow = out + ((size_t)(b * T) + qt * 16 + i) * 64 + dc * 16;
#pragma unroll
        for (int j4 = 0; j4 < 4; ++j4) {
            f4v o;
#pragma unroll
            for (int jj = 0; jj < 4; ++jj) {
                const int d = dc * 16 + j4 * 4 + jj;
                const float* wr = Wp + d * 16;
                float s = 0.f;
#pragma unroll
                for (int h = 0; h < 16; ++h) s += av[h] * wr[h];
                o[jj] = bp[d] + s * inv;
            }
            *(f4v*)(orow + j4 * 4) = o;
        }
    }
}

// ---------------------------------------------------------------------------
// ws layout (bytes): qp 512K | kp 512K | vp 512K   (1.5 MB)
// ---------------------------------------------------------------------------
extern "C" void kernel_launch(void* const* d_in, const int* in_sizes, int n_in,
                              void* d_out, int out_size, void* d_ws, size_t ws_size,
                              hipStream_t stream) {
    const float* idx = (const float*)d_in[0];
    const float* Wk  = (const float*)d_in[1];
    const float* bk  = (const float*)d_in[2];
    const float* Wq  = (const float*)d_in[3];
    const float* bq  = (const float*)d_in[4];
    const float* Wv  = (const float*)d_in[5];
    const float* bv  = (const float*)d_in[6];
    const float* Wp  = (const float*)d_in[7];
    const float* bp  = (const float*)d_in[8];
    float* out = (float*)d_out;

    short* qp = (short*)d_ws;
    short* kp = qp + BATCH * PB;
    short* vp = kp + BATCH * PB;

    k_proj<<<256, 256, 0, stream>>>(idx, Wk, bk, Wq, bq, Wv, bv, qp, kp, vp);
    k_fused<<<512, 256, 0, stream>>>(qp, kp, vp, Wp, bp, out);
}

// Round 9
// 29.826 us; speedup vs baseline: 7.9798x; 1.0434x over previous
//
#include <hip/hip_runtime.h>
#include <hip/hip_bf16.h>
#include <stdint.h>

#define DEV __device__ __forceinline__

typedef short s4v __attribute__((ext_vector_type(4)));   // 4 bf16 (bit pattern)
typedef float f4v __attribute__((ext_vector_type(4)));

static constexpr int T = 4096;
static constexpr int BATCH = 4;
static constexpr int MD = 64;
static constexpr int H = 16;
static constexpr int PB = T * H;        // 65536 permuted elements per batch

// ---------------- mfma 16x16x16 bf16 (D = A[16x16k] * B[16kx16] + C) -------
#if __has_builtin(__builtin_amdgcn_mfma_f32_16x16x16bf16_1k)
DEV f4v mfma16(s4v a, s4v b, f4v c) {
    return __builtin_amdgcn_mfma_f32_16x16x16bf16_1k(a, b, c, 0, 0, 0);
}
#elif __has_builtin(__builtin_amdgcn_mfma_f32_16x16x16_bf16)
typedef __bf16 bf4v __attribute__((ext_vector_type(4)));
DEV f4v mfma16(s4v a, s4v b, f4v c) {
    return __builtin_amdgcn_mfma_f32_16x16x16_bf16(__builtin_bit_cast(bf4v, a),
                                                   __builtin_bit_cast(bf4v, b), c, 0, 0, 0);
}
#else
DEV f4v mfma16(s4v a, s4v b, f4v c) {
    asm("v_mfma_f32_16x16x16_bf16 %0, %1, %2, %0" : "+v"(c) : "v"(a), "v"(b));
    return c;
}
#endif

DEV short f2bf(float x) {               // fp32 -> bf16 RNE (proven)
    uint32_t u = __builtin_bit_cast(uint32_t, x);
    u += 0x7fffu + ((u >> 16) & 1u);
    return (short)(u >> 16);
}

DEV s4v pack4(f4v p) {                  // 4x f2bf — the only proven pack
    return s4v{f2bf(p.x), f2bf(p.y), f2bf(p.z), f2bf(p.w)};
}

DEV float ex2(float x) {
#if __has_builtin(__builtin_amdgcn_exp2f)
    return __builtin_amdgcn_exp2f(x);
#else
    return exp2f(x);
#endif
}

// ---------------------------------------------------------------------------
// K1: QKV projection -> permuted bf16 layout. Q is pre-scaled by 0.25*log2(e)
// so the attention kernel applies exp2 directly to the MFMA output.
// Q/K perm: elem(b,t,h) = b*PB + (t>>4)*256 + (h>>2)*64 + (t&15)*4 + (h&3)
// V   perm: elem(b,t,h) = b*PB + (t>>4)*256 + ((t&15)>>2)*64 + h*4 + (t&3)
// ---------------------------------------------------------------------------
__global__ __launch_bounds__(256) void k_proj(
    const float* __restrict__ idx,
    const float* __restrict__ Wk, const float* __restrict__ bk,
    const float* __restrict__ Wq, const float* __restrict__ bq,
    const float* __restrict__ Wv, const float* __restrict__ bv,
    short* __restrict__ qp, short* __restrict__ kp, short* __restrict__ vp)
{
    const int w = threadIdx.x >> 6, lane = threadIdx.x & 63;
    const int a = lane & 15, g = lane >> 4;
    const int tile = blockIdx.x * 4 + w;        // 0..1023
    const int b = tile >> 8;
    const int trow0 = (tile & 255) << 4;

    const float* rb = idx + (size_t)(b * T + trow0) * MD;

    s4v xf[4], wqf[4], wkf[4], wvf[4];
#pragma unroll
    for (int kc = 0; kc < 4; ++kc) {
        const int ko = kc * 16 + 4 * g;
        f4v x = *(const f4v*)(rb + a * MD + ko);     // idx[t0+a][ko..ko+3]
        f4v q = *(const f4v*)(Wq + a * MD + ko);     // Wq[a][ko..]
        f4v k = *(const f4v*)(Wk + a * MD + ko);
        f4v v = *(const f4v*)(Wv + a * MD + ko);
        xf[kc]  = pack4(x);
        wqf[kc] = pack4(q);
        wkf[kc] = pack4(k);
        wvf[kc] = pack4(v);
    }
    f4v aq = {0.f,0.f,0.f,0.f}, ak = {0.f,0.f,0.f,0.f}, av = {0.f,0.f,0.f,0.f};
#pragma unroll
    for (int kc = 0; kc < 4; ++kc) {
        aq = mfma16(wqf[kc], xf[kc], aq);   // D^T[h][t]: lane t=t0+a, h=4g+r
        ak = mfma16(wkf[kc], xf[kc], ak);
        av = mfma16(xf[kc], wvf[kc], av);   // D[t][h]: lane h=a, t=t0+4g+r
    }
    const int slot = b * PB + (tile & 255) * 256 + g * 64 + a * 4;
    f4v bqv = *(const f4v*)(bq + 4 * g);
    f4v bkv = *(const f4v*)(bk + 4 * g);
    const float bvs = bv[a];
    const float CS = 0.36067376022224085f;      // 0.25 * log2(e), folded into Q
    f4v qv = {(aq.x + bqv.x) * CS, (aq.y + bqv.y) * CS,
              (aq.z + bqv.z) * CS, (aq.w + bqv.w) * CS};
    f4v kv = {ak.x + bkv.x, ak.y + bkv.y, ak.z + bkv.z, ak.w + bkv.w};
    f4v vv = {av.x + bvs, av.y + bvs, av.z + bvs, av.w + bvs};
    *(s4v*)(qp + slot) = pack4(qv);
    *(s4v*)(kp + slot) = pack4(kv);
    *(s4v*)(vp + slot) = pack4(vv);
}

// ---------------------------------------------------------------------------
// Attention over s-tiles [lo, hi) for one Q fragment.
// 8-tile groups, ping-pong prefetch (16 loads in flight under compute).
// Only the LAST group runs the guarded+causal-masked path; its loads are
// index-clamped to hi-1 (valid, finite memory) and padded tiles contribute
// exactly 0 (guard st+u < hi).
// ---------------------------------------------------------------------------
DEV void proc_range(int lo, int hi, s4v Qf, int tq, int g,
                    const short* __restrict__ kb, const short* __restrict__ vb,
                    f4v& acc, float& lp)
{
    if (lo >= hi) return;
    const int ng = (hi - lo + 7) >> 3;
    s4v KA[8], VA[8], KB[8], VB[8];

    auto LOADG = [&](s4v* K, s4v* V, int gi) {
        const int st = lo + gi * 8;
#pragma unroll
        for (int u = 0; u < 8; ++u) {
            const int idx = min(st + u, hi - 1);      // clamp tail padding
            K[u] = *(const s4v*)(kb + idx * 256);
            V[u] = *(const s4v*)(vb + idx * 256);
        }
    };
    auto COMPG = [&](const s4v* K, const s4v* V, int gi) {
        const int st = lo + gi * 8;
        if (gi == ng - 1) {                 // tail group: guarded + masked
#pragma unroll
            for (int u = 0; u < 8; ++u) {
                if (st + u < hi) {
                    f4v S = mfma16(K[u], Qf, f4v{0.f,0.f,0.f,0.f});
                    const int sb = (st + u) * 16 + 4 * g;
                    f4v p;
#pragma unroll
                    for (int r = 0; r < 4; ++r) {
                        const float e = ex2(S[r]);
                        p[r] = (sb + r <= tq) ? e : 0.f;
                    }
                    lp += p.x + p.y + p.z + p.w;
                    acc = mfma16(pack4(p), V[u], acc);
                }
            }
        } else {                            // full group: mask-free fast path
#pragma unroll
            for (int u = 0; u < 8; ++u) {
                f4v S = mfma16(K[u], Qf, f4v{0.f,0.f,0.f,0.f});
                f4v p;
#pragma unroll
                for (int r = 0; r < 4; ++r) p[r] = ex2(S[r]);
                lp += p.x + p.y + p.z + p.w;
                acc = mfma16(pack4(p), V[u], acc);
            }
        }
    };

    int it = 0;
    LOADG(KA, VA, 0);
    for (; it + 2 <= ng; it += 2) {
        LOADG(KB, VB, it + 1);
        COMPG(KA, VA, it);
        if (it + 2 < ng) LOADG(KA, VA, it + 2);
        COMPG(KB, VB, it + 1);
    }
    if (it < ng) COMPG(KA, VA, it);
}

// ---------------------------------------------------------------------------
// K2 (fused): attention + block-local combine + output projection.
// Grid 512 = (b:4) x (pair j:128), 512 THREADS = 8 waves (round 9: 2x TLP,
// 4 waves/SIMD at 2 blocks/CU — was 2 waves/SIMD with 4-wave blocks).
// Block owns q-tiles {j, 255-j}: (j+1) + (256-j) = 257 tiles, split into 8
// balanced slices (257*w)>>3 (32-33 tiles each). Partials combined via LDS
// with one __syncthreads (block-local; no device fence, no atomics).
// ---------------------------------------------------------------------------
__global__ __launch_bounds__(512, 4) void k_fused(
    const short* __restrict__ qp, const short* __restrict__ kp,
    const short* __restrict__ vp,
    const float* __restrict__ Wp, const float* __restrict__ bp,
    float* __restrict__ out)
{
    const int bx = blockIdx.x;
    const int b = bx >> 7, j = bx & 127;
    const int tid = threadIdx.x;
    const int w = tid >> 6, lane = tid & 63;
    const int a = lane & 15, g = lane >> 4;

    const int qtA = j, qtB = 255 - j;
    const int ntA = j + 1;               // A s-tiles: [0, ntA)
    const int ntot = 257;                // ntA + (256 - j)

    const short* qb = qp + b * PB;
    const short* kb = kp + b * PB + g * 64 + a * 4;
    const short* vb = vp + b * PB + g * 64 + a * 4;

    const s4v QfA = *(const s4v*)(qb + qtA * 256 + g * 64 + a * 4);
    const s4v QfB = *(const s4v*)(qb + qtB * 256 + g * 64 + a * 4);
    const int tqA = qtA * 16 + a, tqB = qtB * 16 + a;

    // this wave's balanced slice of the virtual tile list
    const int vLo = (ntot * w) >> 3;
    const int vHi = (ntot * (w + 1)) >> 3;

    f4v accA = {0.f,0.f,0.f,0.f}, accB = {0.f,0.f,0.f,0.f};
    float lpA = 0.f, lpB = 0.f;

    // A part: virtual [vLo, min(vHi,ntA)) -> st same range
    proc_range(vLo, min(vHi, ntA), QfA, tqA, g, kb, vb, accA, lpA);
    // B part: virtual [max(vLo,ntA), vHi) -> st = vt - ntA
    proc_range(max(vLo - ntA, 0), vHi - ntA, QfB, tqB, g, kb, vb, accB, lpB);

    __shared__ float pacc[16 * 64 * 4];  // [(w*2+X)*64 + lane][r]
    __shared__ float plp[16 * 16];       // [(w*2+X)*16 + row]

    *(f4v*)&pacc[((w * 2 + 0) * 64 + lane) * 4] = accA;
    *(f4v*)&pacc[((w * 2 + 1) * 64 + lane) * 4] = accB;

    float lA = lpA + __shfl_xor(lpA, 16); lA += __shfl_xor(lA, 32);
    float lB = lpB + __shfl_xor(lpB, 16); lB += __shfl_xor(lB, 32);
    if (lane < 16) {
        plp[(w * 2 + 0) * 16 + lane] = lA;
        plp[(w * 2 + 1) * 16 + lane] = lB;
    }
    __syncthreads();

    // combine + normalize + output projection: 128 tasks = (X:2, row:16, dc:4)
    if (tid < 128) {
        const int X = tid >> 6, i = (tid >> 2) & 15, dc = tid & 3;
        float av[16];
#pragma unroll
        for (int h = 0; h < 16; ++h) av[h] = 0.f;
        float l = 0.f;
#pragma unroll
        for (int ww = 0; ww < 8; ++ww) {     // fixed wave order: deterministic
            const int base = ((ww * 2 + X) * 64 + (i >> 2) * 16) * 4 + (i & 3);
#pragma unroll
            for (int h = 0; h < 16; ++h) av[h] += pacc[base + h * 4];
            l += plp[(ww * 2 + X) * 16 + i];
        }
        const float inv = 1.f / l;
        const int qt = X ? qtB : qtA;

        float* orow = out + ((size_t)(b * T) + qt * 16 + i) * 64 + dc * 16;
#pragma unroll
        for (int j4 = 0; j4 < 4; ++j4) {
            f4v o;
#pragma unroll
            for (int jj = 0; jj < 4; ++jj) {
                const int d = dc * 16 + j4 * 4 + jj;
                const float* wr = Wp + d * 16;
                float s = 0.f;
#pragma unroll
                for (int h = 0; h < 16; ++h) s += av[h] * wr[h];
                o[jj] = bp[d] + s * inv;
            }
            *(f4v*)(orow + j4 * 4) = o;
        }
    }
}

// ---------------------------------------------------------------------------
// ws layout (bytes): qp 512K | kp 512K | vp 512K   (1.5 MB)
// ---------------------------------------------------------------------------
extern "C" void kernel_launch(void* const* d_in, const int* in_sizes, int n_in,
                              void* d_out, int out_size, void* d_ws, size_t ws_size,
                              hipStream_t stream) {
    const float* idx = (const float*)d_in[0];
    const float* Wk  = (const float*)d_in[1];
    const float* bk  = (const float*)d_in[2];
    const float* Wq  = (const float*)d_in[3];
    const float* bq  = (const float*)d_in[4];
    const float* Wv  = (const float*)d_in[5];
    const float* bv  = (const float*)d_in[6];
    const float* Wp  = (const float*)d_in[7];
    const float* bp  = (const float*)d_in[8];
    float* out = (float*)d_out;

    short* qp = (short*)d_ws;
    short* kp = qp + BATCH * PB;
    short* vp = kp + BATCH * PB;

    k_proj<<<256, 256, 0, stream>>>(idx, Wk, bk, Wq, bq, Wv, bv, qp, kp, vp);
    k_fused<<<512, 512, 0, stream>>>(qp, kp, vp, Wp, bp, out);
}